// Round 11
// baseline (89.377 us; speedup 1.0000x reference)
//
#include <hip/hip_runtime.h>
#include <hip/hip_bf16.h>
#include <math.h>

// Problem constants
#define BATCH   256
#define KMEM    10          // K (class size)
#define NPROT   200         // N*K prototypes per batch elem
#define DDIM    512
#define TINVF   10.0f       // 1/T
#define KSLAB   64          // K-columns staged per slab
#define NSLAB   (DDIM / KSLAB)   // 8
#define RPAD    256         // rows padded to 16 fragments
#define ROWB    128         // bytes per LDS row (64 bf16)
#define NSEG    800         // 200 rows x 4 segments of 16 floats

typedef __attribute__((ext_vector_type(8))) short short8;
typedef __attribute__((ext_vector_type(4))) float f32x4;

// 16 fp32 -> 16 bf16 via v_cvt_pk_bf16_f32 (RNE) + exact fp32 sum-of-squares.
__device__ __forceinline__ void pack16cvt(const float4 c[4], uint4& p0, uint4& p1, float& sq) {
    const float* f = (const float*)c;
    unsigned r[8];
    #pragma unroll
    for (int e = 0; e < 8; e++) {
        float lo = f[2 * e], hi = f[2 * e + 1];
        sq = fmaf(lo, lo, sq);
        sq = fmaf(hi, hi, sq);
        asm("v_cvt_pk_bf16_f32 %0, %1, %2" : "=v"(r[e]) : "v"(lo), "v"(hi));
    }
    p0 = make_uint4(r[0], r[1], r[2], r[3]);
    p1 = make_uint4(r[4], r[5], r[6], r[7]);
}

// One block per batch element, 512 threads = 8 waves (4x2 wave grid), each
// wave computes 4x8 16x16 fragments of the padded 256x256 Gram.
// G_raw = Praw . Praw^T via MFMA on bf16; normalization, diagonal skip,
// class masks, exp/log in the epilogue.
//
// KEY STRUCTURE (rounds 5-10 lesson): __syncthreads() drains vmcnt(0), which
// serialized every phase's global-load burst against compute. The K-loop
// barrier here is s_waitcnt lgkmcnt(0) + raw s_barrier (LDS writes visible;
// global loads NOT drained -- they target private VGPRs only), and the next
// slab's loads are issued AFTER the barrier so they stream during the MFMA
// phase. Two named reg sets give ~2 phases of latency cover.
// Correctness of barrier: lgkmcnt(0) also retires this thread's pending
// ds_reads, so buf[s&1] can't be overwritten while still being read.
__global__ __launch_bounds__(512) void kmain(const float* __restrict__ P,
                                             float* __restrict__ partial) {
    __shared__ char  slab[2][RPAD * ROWB];   // 64 KB, XOR-swizzled bf16 tiles
    __shared__ float normpart[NSEG];
    __shared__ float invn_s[RPAD];
    __shared__ float s1buf[2][RPAD];
    __shared__ float s2buf[2][RPAD];
    __shared__ float red[512];

    const int tid  = threadIdx.x;
    const int lane = tid & 63;
    const int wave = tid >> 6;   // 0..7
    const int wr   = wave >> 1;  // 0..3 : i-frags [wr*4, wr*4+4)
    const int wc   = wave & 1;   // 0..1 : j-frags [wc*8, wc*8+8)
    const int b    = blockIdx.x;
    const float* Pb = P + (size_t)b * NPROT * DDIM;

    // zero pad rows 200..255 in BOTH buffers (never rewritten)
    for (int z = tid; z < 2 * 56 * 8; z += 512) {
        int bsel = z / (56 * 8);
        int slot = z % (56 * 8);
        int row  = NPROT + (slot >> 3);
        *(uint4*)(&slab[bsel][row * ROWB + (slot & 7) * 16]) = make_uint4(0, 0, 0, 0);
    }

    // staging assignment: seg idx -> (row, 16-float segment)
    const int  idx0 = tid;                 // < 800 always
    const int  row0 = idx0 >> 2, seg0 = idx0 & 3;
    const int  idx1 = tid + 512;
    const bool has1 = (idx1 < NSEG);       // threads 0..287
    const int  row1 = idx1 >> 2, seg1 = idx1 & 3;
    const int  swz0 = (row0 & 7) << 4;
    const int  swz1 = (row1 & 7) << 4;

    float sq0 = 0.f, sq1 = 0.f;

    // prologue: load slab 0 into set A, slab 1 into set B
    float4 A0[4], A1[4], B0[4], B1[4];
    {
        const float4* s0 = (const float4*)(Pb + (size_t)row0 * DDIM + seg0 * 16);
        A0[0] = s0[0]; A0[1] = s0[1]; A0[2] = s0[2]; A0[3] = s0[3];
        const float4* s1p = (const float4*)(Pb + (size_t)row0 * DDIM + KSLAB + seg0 * 16);
        B0[0] = s1p[0]; B0[1] = s1p[1]; B0[2] = s1p[2]; B0[3] = s1p[3];
        if (has1) {
            const float4* t0 = (const float4*)(Pb + (size_t)row1 * DDIM + seg1 * 16);
            A1[0] = t0[0]; A1[1] = t0[1]; A1[2] = t0[2]; A1[3] = t0[3];
            const float4* t1 = (const float4*)(Pb + (size_t)row1 * DDIM + KSLAB + seg1 * 16);
            B1[0] = t1[0]; B1[1] = t1[1]; B1[2] = t1[2]; B1[3] = t1[3];
        }
    }

    f32x4 acc[4][8];
    #pragma unroll
    for (int i = 0; i < 4; i++)
        #pragma unroll
        for (int j = 0; j < 8; j++)
            acc[i][j] = (f32x4)(0.f);

    // One phase: pack SET -> buf[S&1]; lgkm-only barrier; issue SET <- slab
    // S+2 (streams during MFMA); MFMA over buf[S&1].
#define PHASE(SET0, SET1, S) do {                                              \
        char* buf = slab[(S) & 1];                                             \
        {                                                                      \
            uint4 p0, p1;                                                      \
            pack16cvt(SET0, p0, p1, sq0);                                      \
            int byte0 = row0 * ROWB + seg0 * 32;                               \
            *(uint4*)(&buf[(byte0     ) ^ swz0]) = p0;                         \
            *(uint4*)(&buf[(byte0 + 16) ^ swz0]) = p1;                         \
        }                                                                      \
        if (has1) {                                                            \
            uint4 p0, p1;                                                      \
            pack16cvt(SET1, p0, p1, sq1);                                      \
            int byte0 = row1 * ROWB + seg1 * 32;                               \
            *(uint4*)(&buf[(byte0     ) ^ swz1]) = p0;                         \
            *(uint4*)(&buf[(byte0 + 16) ^ swz1]) = p1;                         \
        }                                                                      \
        asm volatile("s_waitcnt lgkmcnt(0)" ::: "memory");                     \
        __builtin_amdgcn_s_barrier();                                          \
        if ((S) + 2 < NSLAB) {                                                 \
            const float4* sA = (const float4*)(Pb + (size_t)row0 * DDIM + ((S) + 2) * KSLAB + seg0 * 16); \
            SET0[0] = sA[0]; SET0[1] = sA[1]; SET0[2] = sA[2]; SET0[3] = sA[3];\
            if (has1) {                                                        \
                const float4* sB = (const float4*)(Pb + (size_t)row1 * DDIM + ((S) + 2) * KSLAB + seg1 * 16); \
                SET1[0] = sB[0]; SET1[1] = sB[1]; SET1[2] = sB[2]; SET1[3] = sB[3]; \
            }                                                                  \
        }                                                                      \
        _Pragma("unroll")                                                      \
        for (int ks = 0; ks < 2; ks++) {                                       \
            const int kb = (ks * 32 + (lane >> 4) * 8) * 2;                    \
            short8 af[4];                                                      \
            _Pragma("unroll")                                                  \
            for (int i = 0; i < 4; i++) {                                      \
                int row = (wr * 4 + i) * 16 + (lane & 15);                     \
                af[i] = *(const short8*)(&buf[(row * ROWB + kb) ^ ((row & 7) << 4)]); \
            }                                                                  \
            _Pragma("unroll")                                                  \
            for (int j = 0; j < 8; j++) {                                      \
                int row = (wc * 8 + j) * 16 + (lane & 15);                     \
                short8 bfr = *(const short8*)(&buf[(row * ROWB + kb) ^ ((row & 7) << 4)]); \
                _Pragma("unroll")                                              \
                for (int i = 0; i < 4; i++)                                    \
                    acc[i][j] = __builtin_amdgcn_mfma_f32_16x16x32_bf16(af[i], bfr, acc[i][j], 0, 0, 0); \
            }                                                                  \
        }                                                                      \
    } while (0)

    for (int s2 = 0; s2 < NSLAB / 2; s2++) {
        const int s = 2 * s2;
        PHASE(A0, A1, s);
        PHASE(B0, B1, s + 1);
    }
#undef PHASE

    // ---- norms: 4 seg-partials per row -> invn ----
    normpart[idx0] = sq0;
    if (has1) normpart[idx1] = sq1;
    __syncthreads();
    if (tid < RPAD) {
        float iv = 0.f;
        if (tid < NPROT) {
            float ns = normpart[4 * tid] + normpart[4 * tid + 1]
                     + normpart[4 * tid + 2] + normpart[4 * tid + 3];
            iv = rsqrtf(ns);
        }
        invn_s[tid] = iv;   // 0 for padded rows -> g stays 0
    }
    __syncthreads();

    // ---- epilogue: normalize, mask, exp/class sums, 16-lane reduce ----
    float ijn[8]; int jg[8], jdiv[8];
    #pragma unroll
    for (int j = 0; j < 8; j++) {
        jg[j]   = wc * 128 + j * 16 + (lane & 15);
        ijn[j]  = invn_s[jg[j]];
        jdiv[j] = jg[j] / KMEM;
    }
    #pragma unroll
    for (int i = 0; i < 4; i++) {
        #pragma unroll
        for (int r = 0; r < 4; r++) {
            const int m = wr * 64 + i * 16 + (lane >> 4) * 4 + r;
            const float im = invn_s[m];
            const int mdiv = m / KMEM;
            float s1 = 0.f, s2 = 0.f;
            #pragma unroll
            for (int j = 0; j < 8; j++) {
                float g = acc[i][j][r] * im * ijn[j];
                bool valid = (jg[j] < NPROT) && (m < NPROT) && (jg[j] != m);
                s1 += valid ? __expf(g * TINVF) : 0.f;
                s2 += (valid && (jdiv[j] == mdiv)) ? g : 0.f;
            }
            #pragma unroll
            for (int d = 1; d < 16; d <<= 1) {
                s1 += __shfl_xor(s1, d);
                s2 += __shfl_xor(s2, d);
            }
            if ((lane & 15) == 0) {
                s1buf[wc][m] = s1;
                s2buf[wc][m] = s2;
            }
        }
    }
    __syncthreads();

    // ---- per-anchor loss + block reduction ----
    float v = 0.f;
    if (tid < NPROT) {
        float S1 = s1buf[0][tid] + s1buf[1][tid];
        float S2 = s2buf[0][tid] + s2buf[1][tid];
        v = logf(S1) - S2 * (TINVF / 9.0f);   // /(T*(K-1))
    }
    red[tid] = v;
    __syncthreads();
    for (int sx = 256; sx > 0; sx >>= 1) {
        if (tid < sx) red[tid] += red[tid + sx];
        __syncthreads();
    }
    if (tid == 0) partial[b] = red[0];
}

// final reduction of 256 block partials (fp64) + scale
__global__ __launch_bounds__(256) void kfinal(const float* __restrict__ partial,
                                              float* __restrict__ out) {
    __shared__ double red[256];
    int tid = threadIdx.x;
    red[tid] = (double)partial[tid];
    __syncthreads();
    for (int sx = 128; sx > 0; sx >>= 1) {
        if (tid < sx) red[tid] += red[tid + sx];
        __syncthreads();
    }
    // ALPHA / (BNORM * N * K * D) = 0.1 / 102400
    if (tid == 0) out[0] = (float)(red[0] * (0.1 / 102400.0));
}

extern "C" void kernel_launch(void* const* d_in, const int* in_sizes, int n_in,
                              void* d_out, int out_size, void* d_ws, size_t ws_size,
                              hipStream_t stream) {
    const float* P = (const float*)d_in[0];
    float* partial = (float*)d_ws;   // 256 floats
    float* out     = (float*)d_out;

    kmain<<<BATCH, 512, 0, stream>>>(P, partial);
    kfinal<<<1, 256, 0, stream>>>(partial, out);
}

// Round 12
// 45.575 us; speedup vs baseline: 1.9611x; 1.9611x over previous
//
#include <hip/hip_runtime.h>
#include <hip/hip_bf16.h>
#include <math.h>

// Problem constants
#define BATCH   256
#define KMEM    10          // K (class size)
#define NPROT   200         // N*K prototypes per batch elem
#define DDIM    512
#define TINVF   10.0f       // 1/T
#define KSLAB   64          // K-columns staged per slab
#define NSLAB   (DDIM / KSLAB)   // 8
#define RPAD    256         // rows padded to 16 fragments
#define ROWB    128         // bytes per LDS row (64 bf16)
#define NSEG    800         // 200 rows x 4 segments of 16 floats
#define NBLK    (BATCH * 2) // 2 j-half blocks per batch elem

typedef __attribute__((ext_vector_type(8))) short short8;
typedef __attribute__((ext_vector_type(4))) float f32x4;

// bf16 round-to-nearest-even (finite inputs) -- proven round-5 path
__device__ __forceinline__ unsigned short f2bf(float v) {
    unsigned u = __float_as_uint(v);
    return (unsigned short)((u + 0x7fffu + ((u >> 16) & 1u)) >> 16);
}

__device__ __forceinline__ void pack16(const float4 c[4], uint4& p0, uint4& p1, float& sq) {
    union { unsigned short us[16]; uint4 u[2]; } w;
    const float* f = (const float*)c;
    #pragma unroll
    for (int e = 0; e < 16; e++) {
        float v = f[e];
        sq = fmaf(v, v, sq);
        w.us[e] = f2bf(v);
    }
    p0 = w.u[0];
    p1 = w.u[1];
}

// Two blocks per batch element, split by j-COLUMNS of the Gram (both stage
// the full 256-row slab; the duplicate global reads are L1/L2 hits because
// sibling blocks hb and hb+8 land on the same XCD). 512 threads = 8 waves,
// wave grid 4x2 over (i: 4 frags of 16 rows each x4 = 256 rows,
// j: half's 128 cols as 2 groups of 64). acc[4][4] per wave.
//
// 2 blocks/CU co-resident (LDS ~74 KB x2 <= 160 KB, 16 waves @ <=128 VGPR):
// when one block's __syncthreads drains its staging loads, the sibling's
// MFMA/VALU runs -> implicit overlap (m114), no inline-asm barriers (which
// regressed r10/r11 via compiler spills).
//
// Block mapping: hb -> half = (hb>>3)&1, b = ((hb>>4)<<3)|(hb&7).
// log(S1) needs full-j sums, so kmain writes per-half (S1,S2) to ws;
// kpost combines the two halves and computes the per-anchor loss.
__global__ __launch_bounds__(512) void kmain(const float* __restrict__ P,
                                             float* __restrict__ s12) {
    __shared__ char  slab[2][RPAD * ROWB];   // 64 KB, XOR-swizzled bf16 tiles
    __shared__ float normpart[NSEG];
    __shared__ float invn_s[RPAD];
    __shared__ float s1buf[2][RPAD];
    __shared__ float s2buf[2][RPAD];

    const int tid  = threadIdx.x;
    const int lane = tid & 63;
    const int wave = tid >> 6;   // 0..7
    const int wr   = wave >> 1;  // 0..3 : i-frags [wr*4, wr*4+4)  (rows wr*64..)
    const int wc   = wave & 1;   // 0..1 : j-frag group within the half
    const int hb   = blockIdx.x;
    const int half = (hb >> 3) & 1;
    const int b    = ((hb >> 4) << 3) | (hb & 7);
    const float* Pb = P + (size_t)b * NPROT * DDIM;

    // zero pad rows 200..255 in BOTH buffers (never rewritten)
    for (int z = tid; z < 2 * 56 * 8; z += 512) {
        int bsel = z / (56 * 8);
        int slot = z % (56 * 8);
        int row  = NPROT + (slot >> 3);
        *(uint4*)(&slab[bsel][row * ROWB + (slot & 7) * 16]) = make_uint4(0, 0, 0, 0);
    }

    // staging assignment: seg idx -> (row, 16-float segment)
    const int  idx0 = tid;                 // < 800 always
    const int  row0 = idx0 >> 2, seg0 = idx0 & 3;
    const int  idx1 = tid + 512;
    const bool has1 = (idx1 < NSEG);       // threads 0..287
    const int  row1 = idx1 >> 2, seg1 = idx1 & 3;
    const int  swz0 = (row0 & 7) << 4;
    const int  swz1 = (row1 & 7) << 4;

    float sq0 = 0.f, sq1 = 0.f;

    // prefetch slab 0
    float4 curA[4], curB[4];
    {
        const float4* sA = (const float4*)(Pb + (size_t)row0 * DDIM + seg0 * 16);
        curA[0] = sA[0]; curA[1] = sA[1]; curA[2] = sA[2]; curA[3] = sA[3];
        if (has1) {
            const float4* sB = (const float4*)(Pb + (size_t)row1 * DDIM + seg1 * 16);
            curB[0] = sB[0]; curB[1] = sB[1]; curB[2] = sB[2]; curB[3] = sB[3];
        }
    }

    f32x4 acc[4][4];
    #pragma unroll
    for (int i = 0; i < 4; i++)
        #pragma unroll
        for (int j = 0; j < 4; j++)
            acc[i][j] = (f32x4)(0.f);

    for (int s = 0; s < NSLAB; s++) {
        char* buf = slab[s & 1];

        // ---- convert + swizzled LDS write + sumsq ----
        {
            uint4 p0, p1;
            pack16(curA, p0, p1, sq0);
            int byte0 = row0 * ROWB + seg0 * 32;
            *(uint4*)(&buf[(byte0     ) ^ swz0]) = p0;
            *(uint4*)(&buf[(byte0 + 16) ^ swz0]) = p1;
        }
        if (has1) {
            uint4 p0, p1;
            pack16(curB, p0, p1, sq1);
            int byte0 = row1 * ROWB + seg1 * 32;
            *(uint4*)(&buf[(byte0     ) ^ swz1]) = p0;
            *(uint4*)(&buf[(byte0 + 16) ^ swz1]) = p1;
        }
        __syncthreads();

        // ---- prefetch next slab (overlaps MFMA below; drained at the
        //      NEXT phase's __syncthreads) ----
        float4 nxtA[4], nxtB[4];
        if (s + 1 < NSLAB) {
            const float4* sA = (const float4*)(Pb + (size_t)row0 * DDIM + (s + 1) * KSLAB + seg0 * 16);
            nxtA[0] = sA[0]; nxtA[1] = sA[1]; nxtA[2] = sA[2]; nxtA[3] = sA[3];
            if (has1) {
                const float4* sB = (const float4*)(Pb + (size_t)row1 * DDIM + (s + 1) * KSLAB + seg1 * 16);
                nxtB[0] = sB[0]; nxtB[1] = sB[1]; nxtB[2] = sB[2]; nxtB[3] = sB[3];
            }
        }

        // ---- MFMA: 2 k-steps of 32 over this slab (half-j only) ----
        #pragma unroll
        for (int ks = 0; ks < 2; ks++) {
            const int kb = (ks * 32 + (lane >> 4) * 8) * 2;  // byte offset of k-chunk
            short8 af[4];
            #pragma unroll
            for (int i = 0; i < 4; i++) {
                int row = (wr * 4 + i) * 16 + (lane & 15);
                af[i] = *(const short8*)(&buf[(row * ROWB + kb) ^ ((row & 7) << 4)]);
            }
            #pragma unroll
            for (int j = 0; j < 4; j++) {
                int row = (half * 8 + wc * 4 + j) * 16 + (lane & 15);
                short8 bfr = *(const short8*)(&buf[(row * ROWB + kb) ^ ((row & 7) << 4)]);
                #pragma unroll
                for (int i = 0; i < 4; i++)
                    acc[i][j] = __builtin_amdgcn_mfma_f32_16x16x32_bf16(af[i], bfr, acc[i][j], 0, 0, 0);
            }
        }

        #pragma unroll
        for (int q = 0; q < 4; q++) { curA[q] = nxtA[q]; curB[q] = nxtB[q]; }
    }

    // ---- norms: 4 seg-partials per row -> invn ----
    normpart[idx0] = sq0;
    if (has1) normpart[idx1] = sq1;
    __syncthreads();
    if (tid < RPAD) {
        float iv = 0.f;
        if (tid < NPROT) {
            float ns = normpart[4 * tid] + normpart[4 * tid + 1]
                     + normpart[4 * tid + 2] + normpart[4 * tid + 3];
            iv = rsqrtf(ns);
        }
        invn_s[tid] = iv;   // 0 for padded rows -> g stays 0
    }
    __syncthreads();

    // ---- epilogue: normalize, mask, exp/class sums, 16-lane reduce ----
    float ijn[4]; int jg[4], jdiv[4];
    #pragma unroll
    for (int j = 0; j < 4; j++) {
        jg[j]   = half * 128 + wc * 64 + j * 16 + (lane & 15);
        ijn[j]  = invn_s[jg[j]];
        jdiv[j] = jg[j] / KMEM;
    }
    #pragma unroll
    for (int i = 0; i < 4; i++) {
        #pragma unroll
        for (int r = 0; r < 4; r++) {
            const int m = wr * 64 + i * 16 + (lane >> 4) * 4 + r;
            const float im = invn_s[m];
            const int mdiv = m / KMEM;
            float s1 = 0.f, s2 = 0.f;
            #pragma unroll
            for (int j = 0; j < 4; j++) {
                float g = acc[i][j][r] * im * ijn[j];
                bool valid = (jg[j] < NPROT) && (m < NPROT) && (jg[j] != m);
                s1 += valid ? __expf(g * TINVF) : 0.f;
                s2 += (valid && (jdiv[j] == mdiv)) ? g : 0.f;
            }
            #pragma unroll
            for (int d = 1; d < 16; d <<= 1) {
                s1 += __shfl_xor(s1, d);
                s2 += __shfl_xor(s2, d);
            }
            if ((lane & 15) == 0) {
                s1buf[wc][m] = s1;
                s2buf[wc][m] = s2;
            }
        }
    }
    __syncthreads();

    // ---- write per-half (S1,S2) partials for all 256 m ----
    if (tid < RPAD) {
        float S1 = s1buf[0][tid] + s1buf[1][tid];
        float S2 = s2buf[0][tid] + s2buf[1][tid];
        s12[(size_t)hb * (2 * RPAD) + tid * 2    ] = S1;
        s12[(size_t)hb * (2 * RPAD) + tid * 2 + 1] = S2;
    }
}

// combine the two j-halves, per-anchor loss, per-batch-elem reduction
__global__ __launch_bounds__(256) void kpost(const float* __restrict__ s12,
                                             float* __restrict__ partial2) {
    __shared__ float red[256];
    const int b   = blockIdx.x;
    const int tid = threadIdx.x;
    const int hb0 = ((b >> 3) << 4) | (b & 7);
    const int hb1 = hb0 | 8;
    float v = 0.f;
    if (tid < NPROT) {
        float S1 = s12[(size_t)hb0 * (2 * RPAD) + tid * 2    ]
                 + s12[(size_t)hb1 * (2 * RPAD) + tid * 2    ];
        float S2 = s12[(size_t)hb0 * (2 * RPAD) + tid * 2 + 1]
                 + s12[(size_t)hb1 * (2 * RPAD) + tid * 2 + 1];
        v = logf(S1) - S2 * (TINVF / 9.0f);   // /(T*(K-1))
    }
    red[tid] = v;
    __syncthreads();
    for (int sx = 128; sx > 0; sx >>= 1) {
        if (tid < sx) red[tid] += red[tid + sx];
        __syncthreads();
    }
    if (tid == 0) partial2[b] = red[0];
}

// final reduction of 256 batch partials (fp64) + scale
__global__ __launch_bounds__(256) void kfinal(const float* __restrict__ partial2,
                                              float* __restrict__ out) {
    __shared__ double red[256];
    int tid = threadIdx.x;
    red[tid] = (double)partial2[tid];
    __syncthreads();
    for (int sx = 128; sx > 0; sx >>= 1) {
        if (tid < sx) red[tid] += red[tid + sx];
        __syncthreads();
    }
    // ALPHA / (BNORM * N * K * D) = 0.1 / 102400
    if (tid == 0) out[0] = (float)(red[0] * (0.1 / 102400.0));
}

extern "C" void kernel_launch(void* const* d_in, const int* in_sizes, int n_in,
                              void* d_out, int out_size, void* d_ws, size_t ws_size,
                              hipStream_t stream) {
    const float* P  = (const float*)d_in[0];
    float* s12      = (float*)d_ws;                    // 512 * 512 floats = 1 MB
    float* partial2 = s12 + (size_t)NBLK * (2 * RPAD); // 256 floats
    float* out      = (float*)d_out;

    kmain<<<NBLK, 512, 0, stream>>>(P, s12);
    kpost<<<BATCH, 256, 0, stream>>>(s12, partial2);
    kfinal<<<1, 256, 0, stream>>>(partial2, out);
}